// Round 2
// baseline (52203.351 us; speedup 1.0000x reference)
//
#include <hip/hip_runtime.h>

// MUCMA sequential scan, single wave, registers-only state — round 2:
// one-step lookahead. v(n+1) = <w(n),u(n+1)> - c'(n)*<conj(u(n)),u(n+1)>,
// so the 6 wave reduces for symbol n+1 are independent of symbol n's scalar
// chain and fill its latency bubbles. Emitted v(n) is stored from lane 63,
// where the DPP reduce naturally leaves totals.
//
// Lane roles:
//   lanes 0..37  : (t,j), lane = t*2+j. Hold w[0][j][t], w[1][j][t], load u[t][j].
//   lanes 48..53 : k=0 -> r[0,1,d], z[d][1]   (d = lane-48)
//   lanes 56..61 : k=1 -> r[1,0,d], z[d][0]
// Diagonal r[k,k,*] is dead (masked by 1-eye) and not tracked.

constexpr int   NTAPS  = 19;
constexpr int   FRST   = 38;                  // floats per frame (taps*dims)
constexpr float BETA_C = 0.999f;
constexpr float OMB_C  = 0.001f;              // float32(1 - 0.999), as the reference rounds it
constexpr float LR_C   = 0.0001220703125f;    // 2^-13
constexpr float R2_C   = 1.32f;

template <int CTRL>
__device__ __forceinline__ float dpp_add(float x) {   // x + dpp(x); fusible to v_add_f32_dpp
    return x + __int_as_float(__builtin_amdgcn_update_dpp(
        0, __float_as_int(x), CTRL, 0xF, 0xF, true));
}
template <int CTRL>
__device__ __forceinline__ float dpp_mov(float x) {
    return __int_as_float(__builtin_amdgcn_update_dpp(
        0, __float_as_int(x), CTRL, 0xF, 0xF, true));
}

// Wave-wide sum; total in lane 63.
__device__ __forceinline__ float wave_sum63(float x) {
    x = dpp_add<0x111>(x);   // row_shr:1
    x = dpp_add<0x112>(x);   // row_shr:2
    x = dpp_add<0x114>(x);   // row_shr:4
    x = dpp_add<0x118>(x);   // row_shr:8
    x = dpp_add<0x142>(x);   // row_bcast:15
    x = dpp_add<0x143>(x);   // row_bcast:31
    return x;
}
// 3-level prefix within aligned 8-group; lanes 55/63 get their group's sum.
__device__ __forceinline__ float qsum(float x) {
    x = dpp_add<0x111>(x);
    x = dpp_add<0x112>(x);
    x = dpp_add<0x114>(x);
    return x;
}
__device__ __forceinline__ float rdlane(float x, int l) {
    return __int_as_float(__builtin_amdgcn_readlane(__float_as_int(x), l));
}

__global__ void __launch_bounds__(64, 1)
mucma_scan_kernel(const float* __restrict__ fr_re, const float* __restrict__ fr_im,
                  const float* __restrict__ w0r_in, const float* __restrict__ w0i_in,
                  float* __restrict__ out, int nsym)
{
    const int  lane = threadIdx.x;
    const bool is_w = lane < FRST;
    const int  t = lane >> 1, j = lane & 1;

    float w0r = 0.f, w0i = 0.f, w1r = 0.f, w1i = 0.f;
    if (is_w) {
        w0r = w0r_in[j * NTAPS + t];
        w0i = w0i_in[j * NTAPS + t];
        w1r = w0r_in[FRST + j * NTAPS + t];
        w1i = w0i_in[FRST + j * NTAPS + t];
    }
    float r_re = 0.f, r_im = 0.f, z_re = 0.f, z_im = 0.f;
    float bp = BETA_C;

    const int   d     = lane & 7;
    const bool  gq    = lane >= 56;
    const float qmask = (lane >= 48 && d < 6) ? 1.0f : 0.0f;
    const int   uoff  = is_w ? lane : 0;

    // 8-deep register ring of u frames (slot = n & 7)
    float ure[8], uim[8];
#pragma unroll
    for (int p = 0; p < 8; ++p) {
        int idx = p < nsym ? p : (nsym - 1);
        const float lr = fr_re[idx * FRST + uoff];
        const float li = fr_im[idx * FRST + uoff];
        ure[p] = is_w ? lr : 0.f;
        uim[p] = is_w ? li : 0.f;
    }

    // ---- prologue: v(0) = <w(0), u(0)> ----
    float vv0r, vv0i, vv1r, vv1i;     // lane-63-valid VGPR copies of v(n)
    {
        float p0r = w0r * ure[0] - w0i * uim[0];
        float p0i = w0r * uim[0] + w0i * ure[0];
        float p1r = w1r * ure[0] - w1i * uim[0];
        float p1i = w1r * uim[0] + w1i * ure[0];
        vv0r = wave_sum63(p0r); vv0i = wave_sum63(p0i);
        vv1r = wave_sum63(p1r); vv1i = wave_sum63(p1i);
    }
    float sv0r = rdlane(vv0r, 63), sv0i = rdlane(vv0i, 63);
    float sv1r = rdlane(vv1r, 63), sv1i = rdlane(vv1i, 63);

    auto body = [&](int n, int p, int pnext) {
        // ---- store v(n) (computed last iteration; lives in lane 63) ----
        if (lane == 63) {
            float4 o; o.x = vv0r; o.y = vv0i; o.z = vv1r; o.w = vv1i;
            *reinterpret_cast<float4*>(out + 4 * n) = o;
        }

        const float unr = ure[p],     uni = uim[p];      // u(n)
        const float u1r = ure[pnext], u1i = uim[pnext];  // u(n+1)

        // ---- lookahead reduces: A(n+1) = <w(n),u(n+1)>, s01 = <conj u(n), u(n+1)> ----
        float a0r = w0r * u1r - w0i * u1i;
        float a0i = w0r * u1i + w0i * u1r;
        float a1r = w1r * u1r - w1i * u1i;
        float a1i = w1r * u1i + w1i * u1r;
        float psr = unr * u1r + uni * u1i;
        float psi = unr * u1i - uni * u1r;
        a0r = wave_sum63(a0r); a0i = wave_sum63(a0i);
        a1r = wave_sum63(a1r); a1i = wave_sum63(a1i);
        psr = wave_sum63(psr); psi = wave_sum63(psi);

        // ---- scalar chain for symbol n (uses uniform sv*) ----
        const float vkr = gq ? sv1r : sv0r;
        const float vki = gq ? sv1i : sv0i;
        const float vlr = gq ? sv0r : sv1r;
        const float vli = gq ? sv0i : sv1i;

        const float zsr = dpp_mov<0x111>(z_re);
        const float zsi = dpp_mov<0x111>(z_im);
        z_re = (d == 0) ? vlr : zsr;
        z_im = (d == 0) ? vli : zsi;

        const float ar = OMB_C * vkr, ai = OMB_C * vki;
        r_re = BETA_C * r_re + (ar * z_re + ai * z_im);
        r_im = BETA_C * r_im + (ai * z_re - ar * z_im);

        float qr = (r_re * z_re + r_im * z_im) * qmask;
        float qi = (r_im * z_re - r_re * z_im) * qmask;
        qr = qsum(qr); qi = qsum(qi);

        const float inv = __builtin_amdgcn_rcpf(1.0f - bp);
        bp *= BETA_C;

        const float ek = R2_C - (vkr * vkr + vki * vki);
        const float cr = LR_C * (-2.0f * ek * vkr + 2.0f * inv * qr);
        const float ci = LR_C * (-2.0f * ek * vki + 2.0f * inv * qi);
        const float c0r = rdlane(cr, 55), c0i = rdlane(ci, 55);
        const float c1r = rdlane(cr, 63), c1i = rdlane(ci, 63);

        // ---- v(n+1) = A(n+1) - c'(n)*s01  (valid in lane 63) ----
        vv0r = a0r - (c0r * psr - c0i * psi);
        vv0i = a0i - (c0r * psi + c0i * psr);
        vv1r = a1r - (c1r * psr - c1i * psi);
        vv1i = a1i - (c1r * psi + c1i * psr);
        sv0r = rdlane(vv0r, 63); sv0i = rdlane(vv0i, 63);
        sv1r = rdlane(vv1r, 63); sv1i = rdlane(vv1i, 63);

        // ---- w(n+1) = w(n) - c'(n)*conj(u(n)) ----
        w0r -= c0r * unr + c0i * uni;
        w0i -= c0i * unr - c0r * uni;
        w1r -= c1r * unr + c1i * uni;
        w1i -= c1i * unr - c1r * uni;

        // ---- prefetch u(n+8) into slot p (clamped, branch-free) ----
        {
            int np = n + 8;
            if (np > nsym - 1) np = nsym - 1;
            const float lr = fr_re[np * FRST + uoff];
            const float li = fr_im[np * FRST + uoff];
            ure[p] = is_w ? lr : 0.f;
            uim[p] = is_w ? li : 0.f;
        }
    };

    const int nfull = nsym >> 3;            // full blocks of 8
    for (int b = 0; b < nfull; ++b) {
        const int nb = b << 3;
#pragma unroll
        for (int p = 0; p < 8; ++p) {
            body(nb + p, p, (p + 1) & 7);
        }
    }
    if (nsym & 7) {                          // generic tail (not hit for N=131072)
        const int nb = nsym & ~7;
#pragma unroll
        for (int p = 0; p < 8; ++p) {
            if (nb + p < nsym) body(nb + p, p, (p + 1) & 7);
        }
    }
}

extern "C" void kernel_launch(void* const* d_in, const int* in_sizes, int n_in,
                              void* d_out, int out_size, void* d_ws, size_t ws_size,
                              hipStream_t stream)
{
    const float* fr_re = (const float*)d_in[0];
    const float* fr_im = (const float*)d_in[1];
    const float* w0r   = (const float*)d_in[2];
    const float* w0i   = (const float*)d_in[3];
    float* out = (float*)d_out;
    const int nsym = in_sizes[0] / FRST;
    hipLaunchKernelGGL(mucma_scan_kernel, dim3(1), dim3(64), 0, stream,
                       fr_re, fr_im, w0r, w0i, out, nsym);
}

// Round 3
// 27757.510 us; speedup vs baseline: 1.8807x; 1.8807x over previous
//
#include <hip/hip_runtime.h>

// MUCMA sequential scan, single wave, registers-only — round 3: minimal issue count.
//
// Layout: lane = s + 32*dim, s = 0..31, dim = lane>>5.
//   s in 0..18   : packed taps. Lane holds w[dim][j][t] for elements (2s, 2s+1) of the
//                  frame (t = s, j = 0/1) as float2 (v_pk_* capable), plus u likewise.
//   s in 24..29  : r/z state. dim half 0 -> k=0 (r[0,1,d], z[d][1]), half 1 -> k=1.
//                  d = s-24. q-sums land at lanes 31/63 via 3-level DPP prefix.
// v-reduce: 5 DPP levels reduce each 32-half independently (bcast15 masked to rows 1,3);
// v0 -> lane 31, v1 -> lane 63. All broadcasts via ds_bpermute with constant address
// vectors (own-dim addrA, cross-dim addrB) — no readlane/SGPR round-trips.

typedef float v2f __attribute__((ext_vector_type(2)));

constexpr int   NTAPS  = 19;
constexpr int   FRST   = 38;                  // floats per frame (taps*dims)
constexpr float BETA_C = 0.999f;
constexpr float OMB_C  = 0.001f;              // float32(1 - 0.999) as the reference rounds
constexpr float LR_C   = 0.0001220703125f;    // 2^-13
constexpr float R2_C   = 1.32f;

template <int CTRL, int RMASK = 0xF>
__device__ __forceinline__ float dpp_add(float x) {
    return x + __int_as_float(__builtin_amdgcn_update_dpp(
        0, __float_as_int(x), CTRL, RMASK, 0xF, true));
}
template <int CTRL>
__device__ __forceinline__ float dpp_mov(float x) {
    return __int_as_float(__builtin_amdgcn_update_dpp(
        0, __float_as_int(x), CTRL, 0xF, 0xF, true));
}
__device__ __forceinline__ float bperm(int addr, float x) {
    return __int_as_float(__builtin_amdgcn_ds_bpermute(addr, __float_as_int(x)));
}
// Reduce each 32-lane half independently; half-0 total -> lane 31, half-1 -> lane 63.
// Level 5 (row_bcast:15) is masked to rows 1,3 so row 2 isn't contaminated.
__device__ __forceinline__ float halfred(float x) {
    x = dpp_add<0x111>(x);          // row_shr:1
    x = dpp_add<0x112>(x);          // row_shr:2
    x = dpp_add<0x114>(x);          // row_shr:4
    x = dpp_add<0x118>(x);          // row_shr:8
    x = dpp_add<0x142, 0xA>(x);     // row_bcast:15 into rows 1,3 only
    return x;
}
// 3-level prefix inside aligned 8-groups; group sum at lanes 31 / 63.
__device__ __forceinline__ float qsum8(float x) {
    x = dpp_add<0x111>(x);
    x = dpp_add<0x112>(x);
    x = dpp_add<0x114>(x);
    return x;
}

__global__ void __launch_bounds__(64, 1)
mucma_scan_kernel(const float* __restrict__ fr_re, const float* __restrict__ fr_im,
                  const float* __restrict__ w0r_in, const float* __restrict__ w0i_in,
                  float* __restrict__ out, int nsym)
{
    const int   lane  = threadIdx.x;
    const int   s     = lane & 31;
    const int   dim   = lane >> 5;
    const int   smin  = (s < NTAPS) ? s : (NTAPS - 1);
    const float act   = (s < NTAPS) ? 1.0f : 0.0f;       // masks c' so idle lanes keep w=0
    const int   addrA = 4 * (dim ? 63 : 31);             // own-dim source lane
    const int   addrB = 4 * (dim ? 31 : 63);             // cross-dim source lane
    const bool  d0f   = (s == 24);                       // z-insert lanes (24 and 56)
    const float qmask = (s >= 24 && s < 30) ? 1.0f : 0.0f;
    const bool  is_st = ((lane & 31) == 0);              // lanes 0 and 32 store v

    v2f w_r = {0.f, 0.f}, w_i = {0.f, 0.f};
    if (s < NTAPS) {
        w_r.x = w0r_in[dim * FRST + s];                  // w[dim][0][s]
        w_r.y = w0r_in[dim * FRST + NTAPS + s];          // w[dim][1][s]
        w_i.x = w0i_in[dim * FRST + s];
        w_i.y = w0i_in[dim * FRST + NTAPS + s];
    }
    float r_re = 0.f, r_im = 0.f, z_re = 0.f, z_im = 0.f;
    float bp = BETA_C;

    const int uo = 2 * smin;                             // element offset within frame

    // 8-deep register ring of packed u frames (slot = n & 7)
    v2f rr[8], ri[8];
#pragma unroll
    for (int p = 0; p < 8; ++p) {
        const int idx = (p < nsym) ? p : (nsym - 1);
        rr[p] = *(const v2f*)(fr_re + idx * FRST + uo);
        ri[p] = *(const v2f*)(fr_im + idx * FRST + uo);
    }

    auto body = [&](int n, int p, int npf) {
        const v2f ur = rr[p], ui = ri[p];
        // refill slot p immediately: loads stay in flight ~8 steps
        rr[p] = *(const v2f*)(fr_re + (size_t)npf * FRST + uo);
        ri[p] = *(const v2f*)(fr_im + (size_t)npf * FRST + uo);

        // ---- v = <w, u> : packed products, pair-sum, 5-level half-reduce ----
        const v2f prv = w_r * ur - w_i * ui;
        const v2f piv = w_r * ui + w_i * ur;
        float xr = prv.x + prv.y;
        float xi = piv.x + piv.y;
        xr = halfred(xr);
        xi = halfred(xi);
        const float vkr = bperm(addrA, xr);   // own-dim v (every lane)
        const float vki = bperm(addrA, xi);
        const float vlr = bperm(addrB, xr);   // cross-dim v
        const float vli = bperm(addrB, xi);

        // ---- z shift, insert v_l at d=0 ----
        const float zsr = dpp_mov<0x111>(z_re);
        const float zsi = dpp_mov<0x111>(z_im);
        z_re = d0f ? vlr : zsr;
        z_im = d0f ? vli : zsi;

        // ---- r = beta*r + (1-beta)*v_k*conj(z) ----
        const float ar = OMB_C * vkr, ai = OMB_C * vki;
        r_re = BETA_C * r_re + (ar * z_re + ai * z_im);
        r_im = BETA_C * r_im + (ai * z_re - ar * z_im);

        // ---- mu partials, 3-level group sum -> lanes 31/63 ----
        float qr = (r_re * z_re + r_im * z_im) * qmask;
        float qi = (r_im * z_re - r_re * z_im) * qmask;
        qr = qsum8(qr);
        qi = qsum8(qi);

        // ---- bias correction + c' (valid at lanes 31/63) ----
        const float inv = __builtin_amdgcn_rcpf(1.0f - bp);
        bp *= BETA_C;
        const float i2  = (2.0f * LR_C) * inv;
        const float ek  = R2_C - (vkr * vkr + vki * vki);
        const float ek2 = (-2.0f * LR_C) * ek;
        const float crv = ek2 * vkr + i2 * qr;
        const float civ = ek2 * vki + i2 * qi;
        const float ccr = bperm(addrA, crv) * act;
        const float cci = bperm(addrA, civ) * act;

        // ---- w -= c' * conj(u) (packed) ----
        const v2f c_r = {ccr, ccr};
        const v2f c_i = {cci, cci};
        w_r = w_r - c_r * ur - c_i * ui;
        w_i = w_i - c_i * ur + c_r * ui;

        // ---- emit v(n): lanes 0 and 32 store their dim's (re,im) pair ----
        if (is_st) {
            v2f o; o.x = vkr; o.y = vki;
            *(v2f*)(out + 4 * (size_t)n + 2 * dim) = o;
        }
    };

    int NBmain = nsym / 8 - 1;                 // blocks with unclamped prefetch
    if (NBmain < 0) NBmain = 0;
    for (int b = 0; b < NBmain; ++b) {
        const int nb = b * 8;
#pragma unroll
        for (int p = 0; p < 8; ++p) body(nb + p, p, nb + p + 8);
    }
    // drain: clamped prefetch, static ring indices (no runtime-indexed arrays)
    for (int nb = NBmain * 8; nb < nsym; nb += 8) {
#pragma unroll
        for (int p = 0; p < 8; ++p) {
            const int n = nb + p;
            if (n < nsym) {
                int npf = n + 8;
                if (npf > nsym - 1) npf = nsym - 1;
                body(n, p, npf);
            }
        }
    }
}

extern "C" void kernel_launch(void* const* d_in, const int* in_sizes, int n_in,
                              void* d_out, int out_size, void* d_ws, size_t ws_size,
                              hipStream_t stream)
{
    const float* fr_re = (const float*)d_in[0];
    const float* fr_im = (const float*)d_in[1];
    const float* w0r   = (const float*)d_in[2];
    const float* w0i   = (const float*)d_in[3];
    float* outp = (float*)d_out;
    const int nsym = in_sizes[0] / FRST;
    hipLaunchKernelGGL(mucma_scan_kernel, dim3(1), dim3(64), 0, stream,
                       fr_re, fr_im, w0r, w0i, outp, nsym);
}